// Round 11
// baseline (1447.582 us; speedup 1.0000x reference)
//
#include <hip/hip_runtime.h>
#include <cstddef>
#include <cstdint>

typedef _Float16 half8 __attribute__((ext_vector_type(8)));
typedef float f32x4 __attribute__((ext_vector_type(4)));

#define S_LEN 128
#define B_SZ  64
#define E_SZ  1024
#define NLBL  5
#define NPHASE 129

// ---------------- ws layouts (bytes) ----------------
#define WOFF_WREC  0ull
#define WOFF_WINP  25165824ull
#define WOFF_X16   50331648ull
// MODE0 (history): h0 [2][129][64][1024] f16, h1 same
#define M0_H0    67108864ull
#define M0_H1    100925440ull
#define M0_WPART 134742016ull
#define M0_W     138936320ull
#define M0_FLAGS 138969088ull
#define NEED0    139001856ull
// MODE1 (2-buffer): h0 [2][2][64][1024] f16, h1 same
#define M1_H0    67108864ull
#define M1_H1    67633152ull
#define M1_WPART 68157440ull
#define M1_W     72351744ull
#define M1_FLAGS 72384512ull
#define NEED1    72417280ull

struct PP {
  const float* x;
  const float* W[2][3];
  const float* bias[2][3];
  const float* wordW;
  const float* cs0;
  _Float16* wrec;   // [(d*2+l)*64+j16][g*16384 + kc*512 + lane*8 + e] f16
  _Float16* winp;
  _Float16* x16;    // [B][S][E] f16
  _Float16* h0;     // MODE0: [2][129][64][1024]; MODE1: [2][2][64][1024]
  _Float16* h1;
  float* w;         // [64][128]
  float* wpart;     // [2d][64 j16][128 t][64 b]
  int* flags;       // [2d][128] stride-32 ints (128B)
};

__device__ __forceinline__ uint32_t pack2f16(float a, float b) {
  return (uint32_t)__builtin_bit_cast(unsigned short, (_Float16)a) |
         ((uint32_t)__builtin_bit_cast(unsigned short, (_Float16)b) << 16);
}

__device__ __forceinline__ float fast_sigmoid(float x) {
  return 1.f / (1.f + __expf(-x));
}
__device__ __forceinline__ float fast_tanh(float x) {
  return 1.f - 2.f / (__expf(2.f * x) + 1.f);   // saturates to +/-1, NaN-free
}

#define MFMA16(A, B, C) __builtin_amdgcn_mfma_f32_16x16x32_f16(A, B, C, 0, 0, 0)

// ---- issue asm primitives (outputs only -> no tied operands) ----
#define S_ISSUE_A4C(Q, P0, P1, P2, P3)                                     \
  asm volatile("global_load_dwordx4 %0, %4, off sc0 sc1\n\t"               \
               "global_load_dwordx4 %1, %5, off sc0 sc1\n\t"               \
               "global_load_dwordx4 %2, %6, off sc0 sc1\n\t"               \
               "global_load_dwordx4 %3, %7, off sc0 sc1"                   \
               : "=&v"((Q)[0]), "=&v"((Q)[1]), "=&v"((Q)[2]), "=&v"((Q)[3]) \
               : "v"(P0), "v"(P1), "v"(P2), "v"(P3))

#define S_ISSUE_A4P(Q, P0, P1, P2, P3)                                     \
  asm volatile("global_load_dwordx4 %0, %4, off\n\t"                       \
               "global_load_dwordx4 %1, %5, off\n\t"                       \
               "global_load_dwordx4 %2, %6, off\n\t"                       \
               "global_load_dwordx4 %3, %7, off"                           \
               : "=&v"((Q)[0]), "=&v"((Q)[1]), "=&v"((Q)[2]), "=&v"((Q)[3]) \
               : "v"(P0), "v"(P1), "v"(P2), "v"(P3))

// counted wait: bare asm + sched_barrier fence (rule-18 pattern)
#define S_WAITV(N)                                                         \
  asm volatile("s_waitcnt vmcnt(" #N ")" ::: "memory");                    \
  __builtin_amdgcn_sched_barrier(0)

// q[0],q[1] = m-tiles @ kcA; q[2],q[3] = m-tiles @ kcA+1; B from LDS
__device__ __forceinline__ void comp_rec2s(const uint4* q, int kcA,
                                           const _Float16* wlds, int l64,
                                           f32x4 acc[3][2]) {
  #pragma unroll
  for (int s = 0; s < 2; ++s) {
    const int kc = kcA + s;
    const half8 a0 = __builtin_bit_cast(half8, q[s * 2 + 0]);
    const half8 a1 = __builtin_bit_cast(half8, q[s * 2 + 1]);
    #pragma unroll
    for (int g = 0; g < 3; ++g) {
      const half8 bf = *(const half8*)(wlds + ((size_t)(g * 32 + kc) * 64 + l64) * 8);
      acc[g][0] = MFMA16(a0, bf, acc[g][0]);
      acc[g][1] = MFMA16(a1, bf, acc[g][1]);
    }
  }
}

// B from registers (winp slice)
__device__ __forceinline__ void comp_inp2(const uint4* aq, const uint4* wq,
                                          f32x4 acc[3][2]) {
  #pragma unroll
  for (int s = 0; s < 2; ++s) {
    const half8 a0 = __builtin_bit_cast(half8, aq[s * 2 + 0]);
    const half8 a1 = __builtin_bit_cast(half8, aq[s * 2 + 1]);
    #pragma unroll
    for (int g = 0; g < 3; ++g) {
      const half8 bf = __builtin_bit_cast(half8, wq[s * 3 + g]);
      acc[g][0] = MFMA16(a0, bf, acc[g][0]);
      acc[g][1] = MFMA16(a1, bf, acc[g][1]);
    }
  }
}

// -------- conversion kernels (run every launch; deterministic) --------
__global__ __launch_bounds__(256)
void conv_w_kernel(PP p) {
  const int blk = blockIdx.x;           // (((d*2+l)*3+g)*64 + j16)*2 + part
  const int part = blk & 1;
  const int j16 = (blk >> 1) & 63;
  const int rest = blk >> 7;
  const int g = rest % 3;
  const int dl = rest / 3;
  const int l = dl & 1, d = dl >> 1;
  const int tid = threadIdx.x;
  const int l2 = tid & 63, kc0 = tid >> 6;
  const float* W = p.W[d][g] + (size_t)l * 2048 * 1024 + (size_t)(part ? 1024 : 0) * 1024;
  _Float16* out = (part ? p.winp : p.wrec) + (size_t)(dl * 64 + j16) * 49152 + (size_t)g * 16384;
  const int j = j16 * 16 + (l2 & 15);
  const int kbase = (l2 >> 4) * 8;
  #pragma unroll
  for (int ki = 0; ki < 8; ++ki) {
    const int kc = kc0 * 8 + ki;
    const int k0 = kc * 32 + kbase;
    half8 h;
    #pragma unroll
    for (int e2 = 0; e2 < 8; ++e2) h[e2] = (_Float16)W[(size_t)(k0 + e2) * 1024 + j];
    *(half8*)(out + ((size_t)kc * 64 + l2) * 8) = h;
  }
}

__global__ __launch_bounds__(256)
void conv_x_kernel(const float* x, _Float16* x16) {
  const size_t i8 = ((size_t)blockIdx.x * 256 + threadIdx.x) * 8;
  float4 a = *(const float4*)(x + i8);
  float4 b = *(const float4*)(x + i8 + 4);
  half8 h;
  h[0] = (_Float16)a.x; h[1] = (_Float16)a.y; h[2] = (_Float16)a.z; h[3] = (_Float16)a.w;
  h[4] = (_Float16)b.x; h[5] = (_Float16)b.y; h[6] = (_Float16)b.z; h[7] = (_Float16)b.w;
  *(half8*)(x16 + i8) = h;
}

// MODE0: fill slot 0 of h0/h1 hist; MODE1: fill both par buffers. Then flags.
template<int MODE>
__global__ __launch_bounds__(256)
void init2_kernel(PP p, const float* hs) {
  const size_t HU = (MODE == 0) ? 65536 : 131072;  // u32 words per h array
  const size_t i = (size_t)blockIdx.x * 256 + threadIdx.x;
  if (i < 2 * HU) {
    const size_t ai = (i < HU) ? i : i - HU;
    _Float16* dst = (i < HU) ? p.h0 : p.h1;
    const size_t grp = ai >> 15;            // MODE0: d (0..1); MODE1: d*2+par (0..3)
    const size_t be = ai & 32767;           // [64][512] u32
    const size_t b = be >> 9, ec = be & 511;
    const uint32_t v = pack2f16(hs[b * 1024 + ec * 2], hs[b * 1024 + ec * 2 + 1]);
    const size_t u32off = (MODE == 0) ? (grp * 129 * 32768 + be) : (grp * 32768 + be);
    ((uint32_t*)dst)[u32off] = v;
  } else if (i < 2 * HU + 8192) {
    p.flags[i - 2 * HU] = 0;
  }
}

// ---------------- persistent bidirectional LSTM ----------------
template<int MODE>
__global__ __launch_bounds__(512, 2)
void lstm_persist(PP p) {
  extern __shared__ char smem[];
  _Float16* wlds = (_Float16*)smem;            // 98304 B: rec weights
  float* pre  = (float*)(smem + 98304);        // 768 rows x stride 17 f32 = 52224 B
  float* wred = (float*)(smem + 150528);       // 4096 B

  const int tid = threadIdx.x;
  const int l64 = tid & 63, lr = l64 & 15, lg = l64 >> 4;
  const int wv = tid >> 6, kq = wv & 3, mg = wv >> 2;
  const int blk = blockIdx.x;
  const int j16 = blk & 63, l = (blk >> 6) & 1, d = blk >> 7;
  const int idx = blk & 127;
  const int j0 = j16 * 16;

  // kill stale L1/L2 lines from previous graph replays (one buffer_inv/block)
  if (tid == 0)
    (void)__hip_atomic_load(p.flags, __ATOMIC_ACQUIRE, __HIP_MEMORY_SCOPE_AGENT);
  __syncthreads();

  const size_t tileoff = (size_t)((d * 2 + l) * 64 + j16) * 49152;
  {
    const float4* src = (const float4*)(p.wrec + tileoff);
    float4* dst = (float4*)wlds;
    #pragma unroll
    for (int i = 0; i < 12; ++i) dst[tid + i * 512] = src[tid + i * 512];
  }
  const _Float16* wtile = p.winp + tileoff;
  _Float16* hrec_arr = l ? p.h1 : p.h0;

  // ---- winp slice -> registers (96 VGPR), reused all 129 phases ----
  uint4 wreg[24];
  #pragma unroll
  for (int i = 0; i < 24; ++i) {
    const int kcl = i / 3, g = i % 3;
    const int kc = kq * 8 + kcl;
    wreg[i] = *(const uint4*)(wtile + ((size_t)(g * 32 + kc) * 64 + l64) * 8);
  }

  // ---- prologue hoists: bias / wordW / c-state live in registers ----
  const int pr = tid >> 3;          // pointwise row 0..63
  const int pj = (tid & 7) * 2;     // pointwise col pair
  const int pjg = j0 + pj;
  const float bsf0 = p.bias[d][0][l * E_SZ + pjg], bsf1 = p.bias[d][0][l * E_SZ + pjg + 1];
  const float bsi0 = p.bias[d][1][l * E_SZ + pjg], bsi1 = p.bias[d][1][l * E_SZ + pjg + 1];
  const float bsc0 = p.bias[d][2][l * E_SZ + pjg], bsc1 = p.bias[d][2][l * E_SZ + pjg + 1];
  const float ww0 = p.wordW[d * E_SZ + pjg], ww1 = p.wordW[d * E_SZ + pjg + 1];
  float creg0 = p.cs0[(size_t)pr * E_SZ + pjg];
  float creg1 = p.cs0[(size_t)pr * E_SZ + pjg + 1];
  __syncthreads();

  auto hoff = [&](int dd, int s) -> size_t {
    return (MODE == 0) ? ((size_t)dd * 129 + s) * 65536 : ((size_t)(dd * 2 + s)) * 65536;
  };

  // x16 row bases for this thread's m-tiles (l0 only)
  const _Float16* xr0 = p.x16 + (size_t)(mg * 32 + lr) * S_LEN * 1024;
  const _Float16* xr1 = p.x16 + (size_t)(mg * 32 + 16 + lr) * S_LEN * 1024;

  // cross-phase x prefetch buffers (l0): chunks 0,1
  uint4 xq0[4], xq1[4];
  if (l == 0) {
    const int tdn = d ? (S_LEN - 1) : 0;
    const _Float16* a0 = xr0 + (size_t)tdn * 1024;
    const _Float16* a1 = xr1 + (size_t)tdn * 1024;
    const int kk0 = (kq * 8 + 0) * 32 + lg * 8;
    const int kk1 = (kq * 8 + 2) * 32 + lg * 8;
    S_ISSUE_A4P(xq0, a0 + kk0, a1 + kk0, a0 + kk0 + 32, a1 + kk0 + 32);
    S_ISSUE_A4P(xq1, a0 + kk1, a1 + kk1, a0 + kk1 + 32, a1 + kk1 + 32);
  }

  for (int ph = 0; ph < NPHASE; ++ph) {
    const int t = l ? (ph - 1) : ph;
    const bool active = (unsigned)t < (unsigned)S_LEN;
    if (active) {
      const int par = t & 1, prev = par ^ 1;
      const int td = d ? (S_LEN - 1 - t) : t;
      const int rs    = (MODE == 0) ? t : prev;       // recurrent read slot
      const int wslot = (MODE == 0) ? (t + 1) : par;  // write slot
      const int islot = (MODE == 0) ? (t + 1) : par;  // l1 input slot (h0)

      const _Float16* hAf = hrec_arr + hoff(d, rs);
      const _Float16* r0 = hAf + (size_t)(mg * 32 + lr) * 1024;
      const _Float16* r1 = hAf + (size_t)(mg * 32 + 16 + lr) * 1024;

      const f32x4 zero = {0.f, 0.f, 0.f, 0.f};
      f32x4 acc[3][2];
      #pragma unroll
      for (int g = 0; g < 3; ++g) { acc[g][0] = zero; acc[g][1] = zero; }

      auto issue_rec = [&](int c, uint4* Q) {
        const int kk = (kq * 8 + c * 2) * 32 + lg * 8;
        if (MODE == 0) {
          S_ISSUE_A4P(Q, r0 + kk, r1 + kk, r0 + kk + 32, r1 + kk + 32);
        } else {
          S_ISSUE_A4C(Q, r0 + kk, r1 + kk, r0 + kk + 32, r1 + kk + 32);
        }
      };

      uint4 b0[4], b1[4], b2[4];
      if (l == 0) {
        // input chunks 0,1 already in xq0/xq1 (prefetched across barrier)
        const _Float16* a0base = xr0 + (size_t)td * 1024;
        const _Float16* a1base = xr1 + (size_t)td * 1024;
        auto issue_x = [&](int c, uint4* Q) {
          const int kk = (kq * 8 + c * 2) * 32 + lg * 8;
          S_ISSUE_A4P(Q, a0base + kk, a1base + kk, a0base + kk + 32, a1base + kk + 32);
        };
        issue_rec(0, b0); issue_rec(1, b1); issue_rec(2, b2);   // 12 out
        comp_inp2(xq0, &wreg[0], acc);                          // free cover
        comp_inp2(xq1, &wreg[6], acc);
        S_WAITV(8);  comp_rec2s(b0, kq * 8 + 0, wlds, l64, acc); issue_rec(3, b0);
        S_WAITV(8);  comp_rec2s(b1, kq * 8 + 2, wlds, l64, acc); issue_x(2, b1);
        S_WAITV(8);  comp_rec2s(b2, kq * 8 + 4, wlds, l64, acc); issue_x(3, b2);
        S_WAITV(8);  comp_rec2s(b0, kq * 8 + 6, wlds, l64, acc);
        S_WAITV(4);  comp_inp2(b1, &wreg[12], acc);
        S_WAITV(0);  comp_inp2(b2, &wreg[18], acc);
      } else {
        const _Float16* hf = p.h0 + hoff(d, islot);
        const _Float16* a0base = hf + (size_t)(mg * 32 + lr) * 1024;
        const _Float16* a1base = hf + (size_t)(mg * 32 + 16 + lr) * 1024;
        auto issue_a = [&](int c, uint4* Q) {
          const int kk = (kq * 8 + c * 2) * 32 + lg * 8;
          if (MODE == 0) {
            S_ISSUE_A4P(Q, a0base + kk, a1base + kk, a0base + kk + 32, a1base + kk + 32);
          } else {
            S_ISSUE_A4C(Q, a0base + kk, a1base + kk, a0base + kk + 32, a1base + kk + 32);
          }
        };
        issue_rec(0, b0); issue_rec(1, b1); issue_rec(2, b2);
        S_WAITV(8); comp_rec2s(b0, kq * 8 + 0, wlds, l64, acc); issue_rec(3, b0);
        S_WAITV(8); comp_rec2s(b1, kq * 8 + 2, wlds, l64, acc); issue_a(0, b1);
        S_WAITV(8); comp_rec2s(b2, kq * 8 + 4, wlds, l64, acc); issue_a(1, b2);
        S_WAITV(8); comp_rec2s(b0, kq * 8 + 6, wlds, l64, acc); issue_a(2, b0);
        S_WAITV(8); comp_inp2(b1, &wreg[0],  acc); issue_a(3, b1);
        S_WAITV(8); comp_inp2(b2, &wreg[6],  acc);
        S_WAITV(4); comp_inp2(b0, &wreg[12], acc);
        S_WAITV(0); comp_inp2(b1, &wreg[18], acc);
      }

      // ---- reduce kq partials ----
      #pragma unroll
      for (int g = 0; g < 3; ++g)
        #pragma unroll
        for (int mt = 0; mt < 2; ++mt)
          #pragma unroll
          for (int pp = 0; pp < 4; ++pp)
            pre[(((kq * 3 + g) * 64) + (mg * 2 + mt) * 16 + lg * 4 + pp) * 17 + lr] =
                acc[g][mt][pp];
      __syncthreads();

      // ---- pointwise LSTM update (1 row x 2 cols per thread) ----
      float fp0 = bsf0, fp1 = bsf1, ip0 = bsi0, ip1 = bsi1, cp0 = bsc0, cp1 = bsc1;
      #pragma unroll
      for (int k = 0; k < 4; ++k) {
        fp0 += pre[((k * 3 + 0) * 64 + pr) * 17 + pj];
        fp1 += pre[((k * 3 + 0) * 64 + pr) * 17 + pj + 1];
        ip0 += pre[((k * 3 + 1) * 64 + pr) * 17 + pj];
        ip1 += pre[((k * 3 + 1) * 64 + pr) * 17 + pj + 1];
        cp0 += pre[((k * 3 + 2) * 64 + pr) * 17 + pj];
        cp1 += pre[((k * 3 + 2) * 64 + pr) * 17 + pj + 1];
      }
      const float fg0 = fast_sigmoid(fp0), fg1 = fast_sigmoid(fp1);
      const float ig0 = fast_sigmoid(ip0), ig1 = fast_sigmoid(ip1);
      const float gg0 = fast_tanh(cp0), gg1 = fast_tanh(cp1);
      creg0 = creg0 * fg0 + ig0 * gg0;
      creg1 = creg1 * fg1 + ig1 * gg1;
      const float h0v = fast_tanh(creg0) * fg0;   // forget gate reused as output gate
      const float h1v = fast_tanh(creg1) * fg1;

      uint32_t* hdst = (uint32_t*)(hrec_arr + hoff(d, wslot) + (size_t)pr * 1024 + pjg);
      const uint32_t pk = pack2f16(h0v, h1v);
      asm volatile("global_store_dword %0, %1, off sc0 sc1" ::"v"(hdst), "v"(pk) : "memory");
      if (l) {
        wred[pr * 16 + pj] = h0v * ww0;
        wred[pr * 16 + pj + 1] = h1v * ww1;
      }
      // ---- announce phase completion BEFORE wred reduction ----
      __syncthreads();   // drains vmcnt (h stores at coherence point); wred visible
      if (tid == 0) {
        __hip_atomic_store(p.flags + (size_t)(d * 128 + idx) * 32, ph + 1,
                           __ATOMIC_RELAXED, __HIP_MEMORY_SCOPE_AGENT);
        asm volatile("s_waitcnt vmcnt(0)" ::: "memory");
      }
      // ---- word-projection partials (off inter-block critical path) ----
      if (l && tid < 64) {
        const int tdw = d ? (S_LEN - 1 - t) : t;
        float s = 0.f;
        #pragma unroll
        for (int q = 0; q < 16; ++q) s += wred[tid * 16 + q];
        p.wpart[((size_t)(d * 64 + j16) * S_LEN + tdw) * 64 + tid] = s;
      }
    } else {
      __syncthreads();
      if (tid == 0) {
        __hip_atomic_store(p.flags + (size_t)(d * 128 + idx) * 32, ph + 1,
                           __ATOMIC_RELAXED, __HIP_MEMORY_SCOPE_AGENT);
        asm volatile("s_waitcnt vmcnt(0)" ::: "memory");
      }
    }

    // ---- cross-barrier x prefetch for l0's next phase ----
    if (l == 0 && ph + 1 < S_LEN) {
      const int tn = ph + 1;
      const int tdn = d ? (S_LEN - 1 - tn) : tn;
      const _Float16* a0 = xr0 + (size_t)tdn * 1024;
      const _Float16* a1 = xr1 + (size_t)tdn * 1024;
      const int kk0 = (kq * 8 + 0) * 32 + lg * 8;
      const int kk1 = (kq * 8 + 2) * 32 + lg * 8;
      S_ISSUE_A4P(xq0, a0 + kk0, a1 + kk0, a0 + kk0 + 32, a1 + kk0 + 32);
      S_ISSUE_A4P(xq1, a0 + kk1, a1 + kk1, a0 + kk1 + 32, a1 + kk1 + 32);
    }

    // ---- barrier poll: l0/MODE0 waits only its own 64-block group ----
    {
      const int nflags = (MODE == 0 && l == 0) ? 64 : 128;
      if (tid < nflags) {
        const int* fl = p.flags + (size_t)(d * 128 + tid) * 32;
        int f, it = 0;
        do {
          f = __hip_atomic_load(fl, __ATOMIC_RELAXED, __HIP_MEMORY_SCOPE_AGENT);
          if (f >= ph + 1) break;
          __builtin_amdgcn_s_sleep(1);
        } while (++it < (1 << 22));
      }
    }
    __syncthreads();
  }
}

// w[b][t] = word_b + sum over (d,j16) of wpart
__global__ __launch_bounds__(64)
void reduce_w_kernel(const float* wpart, const float* wordb, float* w) {
  const int t = blockIdx.x, b = threadIdx.x;
  float s = wordb[0];
  #pragma unroll 8
  for (int q = 0; q < 128; ++q)
    s += wpart[((size_t)q * S_LEN + t) * 64 + b];
  w[b * S_LEN + t] = s;
}

__global__ __launch_bounds__(320)
void final_kernel(const float* w, const float* predW, const float* predb, float* out) {
  const int tid = threadIdx.x;
  if (tid >= B_SZ * NLBL) return;
  const int b = tid / NLBL, lab = tid % NLBL;
  float s = predb[lab];
  #pragma unroll 8
  for (int t = 0; t < S_LEN; ++t) s += w[b * S_LEN + t] * predW[t * NLBL + lab];
  out[tid] = s;
}

// ================= launcher =================
extern "C" void kernel_launch(void* const* d_in, const int* in_sizes, int n_in,
                              void* d_out, int out_size, void* d_ws, size_t ws_size,
                              hipStream_t stream) {
  char* ws = (char*)d_ws;
  const bool hist = (ws_size >= NEED0);

  PP p;
  p.x = (const float*)d_in[0];
  p.W[0][0] = (const float*)d_in[5];  p.bias[0][0] = (const float*)d_in[6];
  p.W[0][1] = (const float*)d_in[7];  p.bias[0][1] = (const float*)d_in[8];
  p.W[0][2] = (const float*)d_in[9];  p.bias[0][2] = (const float*)d_in[10];
  p.W[1][0] = (const float*)d_in[11]; p.bias[1][0] = (const float*)d_in[12];
  p.W[1][1] = (const float*)d_in[13]; p.bias[1][1] = (const float*)d_in[14];
  p.W[1][2] = (const float*)d_in[15]; p.bias[1][2] = (const float*)d_in[16];
  p.wordW = (const float*)d_in[17];
  p.cs0   = (const float*)d_in[1];
  p.wrec  = (_Float16*)(ws + WOFF_WREC);
  p.winp  = (_Float16*)(ws + WOFF_WINP);
  p.x16   = (_Float16*)(ws + WOFF_X16);
  if (hist) {
    p.h0    = (_Float16*)(ws + M0_H0);
    p.h1    = (_Float16*)(ws + M0_H1);
    p.wpart = (float*)(ws + M0_WPART);
    p.w     = (float*)(ws + M0_W);
    p.flags = (int*)(ws + M0_FLAGS);
  } else {
    p.h0    = (_Float16*)(ws + M1_H0);
    p.h1    = (_Float16*)(ws + M1_H1);
    p.wpart = (float*)(ws + M1_WPART);
    p.w     = (float*)(ws + M1_W);
    p.flags = (int*)(ws + M1_FLAGS);
  }

  hipFuncSetAttribute(reinterpret_cast<const void*>(&lstm_persist<0>),
                      hipFuncAttributeMaxDynamicSharedMemorySize, 155648);
  hipFuncSetAttribute(reinterpret_cast<const void*>(&lstm_persist<1>),
                      hipFuncAttributeMaxDynamicSharedMemorySize, 155648);

  conv_w_kernel<<<1536, 256, 0, stream>>>(p);
  conv_x_kernel<<<4096, 256, 0, stream>>>(p.x, p.x16);
  if (hist) {
    init2_kernel<0><<<544, 256, 0, stream>>>(p, (const float*)d_in[2]);
    lstm_persist<0><<<256, 512, 155648, stream>>>(p);
  } else {
    init2_kernel<1><<<1056, 256, 0, stream>>>(p, (const float*)d_in[2]);
    lstm_persist<1><<<256, 512, 155648, stream>>>(p);
  }
  reduce_w_kernel<<<128, 64, 0, stream>>>(p.wpart, (const float*)d_in[18], p.w);
  final_kernel<<<1, 320, 0, stream>>>(p.w, (const float*)d_in[19],
                                      (const float*)d_in[20], (float*)d_out);
}

// Round 12
// 1319.649 us; speedup vs baseline: 1.0969x; 1.0969x over previous
//
#include <hip/hip_runtime.h>
#include <cstddef>
#include <cstdint>

typedef _Float16 half8 __attribute__((ext_vector_type(8)));
typedef float f32x4 __attribute__((ext_vector_type(4)));

#define S_LEN 128
#define B_SZ  64
#define E_SZ  1024
#define NLBL  5
#define NPHASE 129

// ---------------- ws layouts (bytes) ----------------
#define WOFF_WREC  0ull
#define WOFF_WINP  25165824ull
#define WOFF_X16   50331648ull
// MODE0 (history): h0 [2][129][64][1024] f16, h1 same
#define M0_H0    67108864ull
#define M0_H1    100925440ull
#define M0_WPART 134742016ull
#define M0_W     138936320ull
#define M0_FLAGS 138969088ull
#define NEED0    139001856ull
// MODE1 (2-buffer): h0 [2][2][64][1024] f16, h1 same
#define M1_H0    67108864ull
#define M1_H1    67633152ull
#define M1_WPART 68157440ull
#define M1_W     72351744ull
#define M1_FLAGS 72384512ull
#define NEED1    72417280ull

struct PP {
  const float* x;
  const float* W[2][3];
  const float* bias[2][3];
  const float* wordW;
  const float* cs0;
  _Float16* wrec;   // [(d*2+l)*64+j16][g*16384 + kc*512 + lane*8 + e] f16
  _Float16* winp;
  _Float16* x16;    // [B][S][E] f16
  _Float16* h0;     // MODE0: [2][129][64][1024]; MODE1: [2][2][64][1024]
  _Float16* h1;
  float* w;         // [64][128]
  float* wpart;     // [2d][64 j16][128 t][64 b]
  int* flags;       // [2d][128] stride-32 ints (128B)
};

__device__ __forceinline__ uint32_t pack2f16(float a, float b) {
  return (uint32_t)__builtin_bit_cast(unsigned short, (_Float16)a) |
         ((uint32_t)__builtin_bit_cast(unsigned short, (_Float16)b) << 16);
}

__device__ __forceinline__ float fast_sigmoid(float x) {
  return 1.f / (1.f + __expf(-x));
}
__device__ __forceinline__ float fast_tanh(float x) {
  return 1.f - 2.f / (__expf(2.f * x) + 1.f);   // saturates to +/-1, NaN-free
}

#define MFMA16(A, B, C) __builtin_amdgcn_mfma_f32_16x16x32_f16(A, B, C, 0, 0, 0)

// ---- issue asm primitives (outputs only -> no tied operands) ----
#define S_ISSUE_A4C(Q, P0, P1, P2, P3)                                     \
  asm volatile("global_load_dwordx4 %0, %4, off sc0 sc1\n\t"               \
               "global_load_dwordx4 %1, %5, off sc0 sc1\n\t"               \
               "global_load_dwordx4 %2, %6, off sc0 sc1\n\t"               \
               "global_load_dwordx4 %3, %7, off sc0 sc1"                   \
               : "=&v"((Q)[0]), "=&v"((Q)[1]), "=&v"((Q)[2]), "=&v"((Q)[3]) \
               : "v"(P0), "v"(P1), "v"(P2), "v"(P3))

#define S_ISSUE_A4P(Q, P0, P1, P2, P3)                                     \
  asm volatile("global_load_dwordx4 %0, %4, off\n\t"                       \
               "global_load_dwordx4 %1, %5, off\n\t"                       \
               "global_load_dwordx4 %2, %6, off\n\t"                       \
               "global_load_dwordx4 %3, %7, off"                           \
               : "=&v"((Q)[0]), "=&v"((Q)[1]), "=&v"((Q)[2]), "=&v"((Q)[3]) \
               : "v"(P0), "v"(P1), "v"(P2), "v"(P3))

// counted wait: bare asm + sched_barrier fence (rule-18 pattern)
#define S_WAITV(N)                                                         \
  asm volatile("s_waitcnt vmcnt(" #N ")" ::: "memory");                    \
  __builtin_amdgcn_sched_barrier(0)

// q[0],q[1] = m-tiles @ kcA; q[2],q[3] = m-tiles @ kcA+1; B from LDS
__device__ __forceinline__ void comp_rec2s(const uint4* q, int kcA,
                                           const _Float16* wlds, int l64,
                                           f32x4 acc[3][2]) {
  #pragma unroll
  for (int s = 0; s < 2; ++s) {
    const int kc = kcA + s;
    const half8 a0 = __builtin_bit_cast(half8, q[s * 2 + 0]);
    const half8 a1 = __builtin_bit_cast(half8, q[s * 2 + 1]);
    #pragma unroll
    for (int g = 0; g < 3; ++g) {
      const half8 bf = *(const half8*)(wlds + ((size_t)(g * 32 + kc) * 64 + l64) * 8);
      acc[g][0] = MFMA16(a0, bf, acc[g][0]);
      acc[g][1] = MFMA16(a1, bf, acc[g][1]);
    }
  }
}

// B from registers (winp slice)
__device__ __forceinline__ void comp_inp2(const uint4* aq, const uint4* wq,
                                          f32x4 acc[3][2]) {
  #pragma unroll
  for (int s = 0; s < 2; ++s) {
    const half8 a0 = __builtin_bit_cast(half8, aq[s * 2 + 0]);
    const half8 a1 = __builtin_bit_cast(half8, aq[s * 2 + 1]);
    #pragma unroll
    for (int g = 0; g < 3; ++g) {
      const half8 bf = __builtin_bit_cast(half8, wq[s * 3 + g]);
      acc[g][0] = MFMA16(a0, bf, acc[g][0]);
      acc[g][1] = MFMA16(a1, bf, acc[g][1]);
    }
  }
}

// -------- conversion kernels (run every launch; deterministic) --------
__global__ __launch_bounds__(256)
void conv_w_kernel(PP p) {
  const int blk = blockIdx.x;           // (((d*2+l)*3+g)*64 + j16)*2 + part
  const int part = blk & 1;
  const int j16 = (blk >> 1) & 63;
  const int rest = blk >> 7;
  const int g = rest % 3;
  const int dl = rest / 3;
  const int l = dl & 1, d = dl >> 1;
  const int tid = threadIdx.x;
  const int l2 = tid & 63, kc0 = tid >> 6;
  const float* W = p.W[d][g] + (size_t)l * 2048 * 1024 + (size_t)(part ? 1024 : 0) * 1024;
  _Float16* out = (part ? p.winp : p.wrec) + (size_t)(dl * 64 + j16) * 49152 + (size_t)g * 16384;
  const int j = j16 * 16 + (l2 & 15);
  const int kbase = (l2 >> 4) * 8;
  #pragma unroll
  for (int ki = 0; ki < 8; ++ki) {
    const int kc = kc0 * 8 + ki;
    const int k0 = kc * 32 + kbase;
    half8 h;
    #pragma unroll
    for (int e2 = 0; e2 < 8; ++e2) h[e2] = (_Float16)W[(size_t)(k0 + e2) * 1024 + j];
    *(half8*)(out + ((size_t)kc * 64 + l2) * 8) = h;
  }
}

__global__ __launch_bounds__(256)
void conv_x_kernel(const float* x, _Float16* x16) {
  const size_t i8 = ((size_t)blockIdx.x * 256 + threadIdx.x) * 8;
  float4 a = *(const float4*)(x + i8);
  float4 b = *(const float4*)(x + i8 + 4);
  half8 h;
  h[0] = (_Float16)a.x; h[1] = (_Float16)a.y; h[2] = (_Float16)a.z; h[3] = (_Float16)a.w;
  h[4] = (_Float16)b.x; h[5] = (_Float16)b.y; h[6] = (_Float16)b.z; h[7] = (_Float16)b.w;
  *(half8*)(x16 + i8) = h;
}

// MODE0: fill slot 0 of h0/h1 hist; MODE1: fill both par buffers. Then flags.
template<int MODE>
__global__ __launch_bounds__(256)
void init2_kernel(PP p, const float* hs) {
  const size_t HU = (MODE == 0) ? 65536 : 131072;  // u32 words per h array
  const size_t i = (size_t)blockIdx.x * 256 + threadIdx.x;
  if (i < 2 * HU) {
    const size_t ai = (i < HU) ? i : i - HU;
    _Float16* dst = (i < HU) ? p.h0 : p.h1;
    const size_t grp = ai >> 15;            // MODE0: d (0..1); MODE1: d*2+par (0..3)
    const size_t be = ai & 32767;           // [64][512] u32
    const size_t b = be >> 9, ec = be & 511;
    const uint32_t v = pack2f16(hs[b * 1024 + ec * 2], hs[b * 1024 + ec * 2 + 1]);
    const size_t u32off = (MODE == 0) ? (grp * 129 * 32768 + be) : (grp * 32768 + be);
    ((uint32_t*)dst)[u32off] = v;
  } else if (i < 2 * HU + 8192) {
    p.flags[i - 2 * HU] = 0;
  }
}

// ---------------- persistent bidirectional LSTM ----------------
template<int MODE>
__global__ __launch_bounds__(512, 2)
void lstm_persist(PP p) {
  extern __shared__ char smem[];
  _Float16* wlds = (_Float16*)smem;            // 98304 B: rec weights
  float* pre  = (float*)(smem + 98304);        // 768 rows x stride 17 f32 = 52224 B
  float* wred = (float*)(smem + 150528);       // 4096 B

  const int tid = threadIdx.x;
  const int l64 = tid & 63, lr = l64 & 15, lg = l64 >> 4;
  const int wv = tid >> 6, kq = wv & 3, mg = wv >> 2;
  const int blk = blockIdx.x;
  const int j16 = blk & 63, l = (blk >> 6) & 1, d = blk >> 7;
  const int idx = blk & 127;
  const int j0 = j16 * 16;

  // kill stale L1/L2 lines from previous graph replays (one buffer_inv/block)
  if (tid == 0)
    (void)__hip_atomic_load(p.flags, __ATOMIC_ACQUIRE, __HIP_MEMORY_SCOPE_AGENT);
  __syncthreads();

  const size_t tileoff = (size_t)((d * 2 + l) * 64 + j16) * 49152;
  {
    const float4* src = (const float4*)(p.wrec + tileoff);
    float4* dst = (float4*)wlds;
    #pragma unroll
    for (int i = 0; i < 12; ++i) dst[tid + i * 512] = src[tid + i * 512];
  }
  const _Float16* wtile = p.winp + tileoff;
  _Float16* hrec_arr = l ? p.h1 : p.h0;

  // ---- winp slice -> registers (96 VGPR), reused all 129 phases ----
  uint4 wreg[24];
  #pragma unroll
  for (int i = 0; i < 24; ++i) {
    const int kcl = i / 3, g = i % 3;
    const int kc = kq * 8 + kcl;
    wreg[i] = *(const uint4*)(wtile + ((size_t)(g * 32 + kc) * 64 + l64) * 8);
  }

  // ---- prologue hoists: bias / wordW / c-state live in registers ----
  const int pr = tid >> 3;          // pointwise row 0..63
  const int pj = (tid & 7) * 2;     // pointwise col pair
  const int pjg = j0 + pj;
  const float bsf0 = p.bias[d][0][l * E_SZ + pjg], bsf1 = p.bias[d][0][l * E_SZ + pjg + 1];
  const float bsi0 = p.bias[d][1][l * E_SZ + pjg], bsi1 = p.bias[d][1][l * E_SZ + pjg + 1];
  const float bsc0 = p.bias[d][2][l * E_SZ + pjg], bsc1 = p.bias[d][2][l * E_SZ + pjg + 1];
  const float ww0 = p.wordW[d * E_SZ + pjg], ww1 = p.wordW[d * E_SZ + pjg + 1];
  float creg0 = p.cs0[(size_t)pr * E_SZ + pjg];
  float creg1 = p.cs0[(size_t)pr * E_SZ + pjg + 1];
  __syncthreads();

  auto hoff = [&](int dd, int s) -> size_t {
    return (MODE == 0) ? ((size_t)dd * 129 + s) * 65536 : ((size_t)(dd * 2 + s)) * 65536;
  };

  for (int ph = 0; ph < NPHASE; ++ph) {
    const int t = l ? (ph - 1) : ph;
    const bool active = (unsigned)t < (unsigned)S_LEN;
    if (active) {
      const int par = t & 1, prev = par ^ 1;
      const int td = d ? (S_LEN - 1 - t) : t;
      const int rs    = (MODE == 0) ? t : prev;       // recurrent read slot
      const int wslot = (MODE == 0) ? (t + 1) : par;  // write slot
      const int islot = (MODE == 0) ? (t + 1) : par;  // l1 input slot (h0)

      const _Float16* hAf = hrec_arr + hoff(d, rs);
      const _Float16* r0 = hAf + (size_t)(mg * 32 + lr) * 1024;
      const _Float16* r1 = hAf + (size_t)(mg * 32 + 16 + lr) * 1024;
      const _Float16* a0base;
      const _Float16* a1base;
      if (l == 0) {
        a0base = p.x16 + ((size_t)(mg * 32 + lr) * S_LEN + td) * 1024;
        a1base = p.x16 + ((size_t)(mg * 32 + 16 + lr) * S_LEN + td) * 1024;
      } else {
        const _Float16* hf = p.h0 + hoff(d, islot);
        a0base = hf + (size_t)(mg * 32 + lr) * 1024;
        a1base = hf + (size_t)(mg * 32 + 16 + lr) * 1024;
      }

      const f32x4 zero = {0.f, 0.f, 0.f, 0.f};
      f32x4 acc[3][2];
      #pragma unroll
      for (int g = 0; g < 3; ++g) { acc[g][0] = zero; acc[g][1] = zero; }

      auto issue_rec = [&](int c, uint4* Q) {
        const int kk = (kq * 8 + c * 2) * 32 + lg * 8;
        if (MODE == 0) {
          S_ISSUE_A4P(Q, r0 + kk, r1 + kk, r0 + kk + 32, r1 + kk + 32);
        } else {
          S_ISSUE_A4C(Q, r0 + kk, r1 + kk, r0 + kk + 32, r1 + kk + 32);
        }
      };
      auto issue_a = [&](int c, uint4* Q) {
        const int kk = (kq * 8 + c * 2) * 32 + lg * 8;
        if (MODE == 0 || l == 0) {
          S_ISSUE_A4P(Q, a0base + kk, a1base + kk, a0base + kk + 32, a1base + kk + 32);
        } else {
          S_ISSUE_A4C(Q, a0base + kk, a1base + kk, a0base + kk + 32, a1base + kk + 32);
        }
      };

      // ---- 3-buffer, 8-stage pipeline (s0-3 rec, s4-7 input), vmcnt(8) ----
      uint4 b0[4], b1[4], b2[4];
      issue_rec(0, b0); issue_rec(1, b1); issue_rec(2, b2);
      S_WAITV(8); comp_rec2s(b0, kq * 8 + 0, wlds, l64, acc); issue_rec(3, b0);
      S_WAITV(8); comp_rec2s(b1, kq * 8 + 2, wlds, l64, acc); issue_a(0, b1);
      S_WAITV(8); comp_rec2s(b2, kq * 8 + 4, wlds, l64, acc); issue_a(1, b2);
      S_WAITV(8); comp_rec2s(b0, kq * 8 + 6, wlds, l64, acc); issue_a(2, b0);
      S_WAITV(8); comp_inp2(b1, &wreg[0],  acc); issue_a(3, b1);
      S_WAITV(8); comp_inp2(b2, &wreg[6],  acc);
      S_WAITV(4); comp_inp2(b0, &wreg[12], acc);
      S_WAITV(0); comp_inp2(b1, &wreg[18], acc);

      // ---- reduce kq partials (stride-17: odd stride mixes bank parity) ----
      #pragma unroll
      for (int g = 0; g < 3; ++g)
        #pragma unroll
        for (int mt = 0; mt < 2; ++mt)
          #pragma unroll
          for (int pp = 0; pp < 4; ++pp)
            pre[(((kq * 3 + g) * 64) + (mg * 2 + mt) * 16 + lg * 4 + pp) * 17 + lr] =
                acc[g][mt][pp];
      __syncthreads();

      // ---- pointwise LSTM update (1 row x 2 cols per thread) ----
      float fp0 = bsf0, fp1 = bsf1, ip0 = bsi0, ip1 = bsi1, cp0 = bsc0, cp1 = bsc1;
      #pragma unroll
      for (int k = 0; k < 4; ++k) {
        fp0 += pre[((k * 3 + 0) * 64 + pr) * 17 + pj];
        fp1 += pre[((k * 3 + 0) * 64 + pr) * 17 + pj + 1];
        ip0 += pre[((k * 3 + 1) * 64 + pr) * 17 + pj];
        ip1 += pre[((k * 3 + 1) * 64 + pr) * 17 + pj + 1];
        cp0 += pre[((k * 3 + 2) * 64 + pr) * 17 + pj];
        cp1 += pre[((k * 3 + 2) * 64 + pr) * 17 + pj + 1];
      }
      const float fg0 = fast_sigmoid(fp0), fg1 = fast_sigmoid(fp1);
      const float ig0 = fast_sigmoid(ip0), ig1 = fast_sigmoid(ip1);
      const float gg0 = fast_tanh(cp0), gg1 = fast_tanh(cp1);
      creg0 = creg0 * fg0 + ig0 * gg0;
      creg1 = creg1 * fg1 + ig1 * gg1;
      const float h0v = fast_tanh(creg0) * fg0;   // forget gate reused as output gate
      const float h1v = fast_tanh(creg1) * fg1;

      uint32_t* hdst = (uint32_t*)(hrec_arr + hoff(d, wslot) + (size_t)pr * 1024 + pjg);
      const uint32_t pk = pack2f16(h0v, h1v);
      asm volatile("global_store_dword %0, %1, off sc0 sc1" ::"v"(hdst), "v"(pk) : "memory");
      if (l) {
        wred[pr * 16 + pj] = h0v * ww0;
        wred[pr * 16 + pj + 1] = h1v * ww1;
      }
      // ---- announce completion right after the h-store drain ----
      __syncthreads();   // compiler drains vmcnt before s_barrier -> h visible
      if (tid == 0) {
        __hip_atomic_store(p.flags + (size_t)(d * 128 + idx) * 32, ph + 1,
                           __ATOMIC_RELAXED, __HIP_MEMORY_SCOPE_AGENT);
        asm volatile("s_waitcnt vmcnt(0)" ::: "memory");
      }
      // ---- word-projection partials (off inter-block critical path) ----
      if (l && tid < 64) {
        float s = 0.f;
        #pragma unroll
        for (int q = 0; q < 16; ++q) s += wred[tid * 16 + q];
        p.wpart[((size_t)(d * 64 + j16) * S_LEN + td) * 64 + tid] = s;
      }
    } else {
      __syncthreads();
      if (tid == 0) {
        __hip_atomic_store(p.flags + (size_t)(d * 128 + idx) * 32, ph + 1,
                           __ATOMIC_RELAXED, __HIP_MEMORY_SCOPE_AGENT);
        asm volatile("s_waitcnt vmcnt(0)" ::: "memory");
      }
    }

    // ---- flat 1-hop barrier: parallel poll of all 128 group flags ----
    if (tid < 128) {
      const int* fl = p.flags + (size_t)(d * 128 + tid) * 32;
      int f, it = 0;
      do {
        f = __hip_atomic_load(fl, __ATOMIC_RELAXED, __HIP_MEMORY_SCOPE_AGENT);
        if (f >= ph + 1) break;
        __builtin_amdgcn_s_sleep(1);
      } while (++it < (1 << 22));
    }
    __syncthreads();
  }
}

// w[b][t] = word_b + sum over (d,j16) of wpart
__global__ __launch_bounds__(64)
void reduce_w_kernel(const float* wpart, const float* wordb, float* w) {
  const int t = blockIdx.x, b = threadIdx.x;
  float s = wordb[0];
  #pragma unroll 8
  for (int q = 0; q < 128; ++q)
    s += wpart[((size_t)q * S_LEN + t) * 64 + b];
  w[b * S_LEN + t] = s;
}

__global__ __launch_bounds__(320)
void final_kernel(const float* w, const float* predW, const float* predb, float* out) {
  const int tid = threadIdx.x;
  if (tid >= B_SZ * NLBL) return;
  const int b = tid / NLBL, lab = tid % NLBL;
  float s = predb[lab];
  #pragma unroll 8
  for (int t = 0; t < S_LEN; ++t) s += w[b * S_LEN + t] * predW[t * NLBL + lab];
  out[tid] = s;
}

// ================= launcher =================
extern "C" void kernel_launch(void* const* d_in, const int* in_sizes, int n_in,
                              void* d_out, int out_size, void* d_ws, size_t ws_size,
                              hipStream_t stream) {
  char* ws = (char*)d_ws;
  const bool hist = (ws_size >= NEED0);

  PP p;
  p.x = (const float*)d_in[0];
  p.W[0][0] = (const float*)d_in[5];  p.bias[0][0] = (const float*)d_in[6];
  p.W[0][1] = (const float*)d_in[7];  p.bias[0][1] = (const float*)d_in[8];
  p.W[0][2] = (const float*)d_in[9];  p.bias[0][2] = (const float*)d_in[10];
  p.W[1][0] = (const float*)d_in[11]; p.bias[1][0] = (const float*)d_in[12];
  p.W[1][1] = (const float*)d_in[13]; p.bias[1][1] = (const float*)d_in[14];
  p.W[1][2] = (const float*)d_in[15]; p.bias[1][2] = (const float*)d_in[16];
  p.wordW = (const float*)d_in[17];
  p.cs0   = (const float*)d_in[1];
  p.wrec  = (_Float16*)(ws + WOFF_WREC);
  p.winp  = (_Float16*)(ws + WOFF_WINP);
  p.x16   = (_Float16*)(ws + WOFF_X16);
  if (hist) {
    p.h0    = (_Float16*)(ws + M0_H0);
    p.h1    = (_Float16*)(ws + M0_H1);
    p.wpart = (float*)(ws + M0_WPART);
    p.w     = (float*)(ws + M0_W);
    p.flags = (int*)(ws + M0_FLAGS);
  } else {
    p.h0    = (_Float16*)(ws + M1_H0);
    p.h1    = (_Float16*)(ws + M1_H1);
    p.wpart = (float*)(ws + M1_WPART);
    p.w     = (float*)(ws + M1_W);
    p.flags = (int*)(ws + M1_FLAGS);
  }

  hipFuncSetAttribute(reinterpret_cast<const void*>(&lstm_persist<0>),
                      hipFuncAttributeMaxDynamicSharedMemorySize, 155648);
  hipFuncSetAttribute(reinterpret_cast<const void*>(&lstm_persist<1>),
                      hipFuncAttributeMaxDynamicSharedMemorySize, 155648);

  conv_w_kernel<<<1536, 256, 0, stream>>>(p);
  conv_x_kernel<<<4096, 256, 0, stream>>>(p.x, p.x16);
  if (hist) {
    init2_kernel<0><<<544, 256, 0, stream>>>(p, (const float*)d_in[2]);
    lstm_persist<0><<<256, 512, 155648, stream>>>(p);
  } else {
    init2_kernel<1><<<1056, 256, 0, stream>>>(p, (const float*)d_in[2]);
    lstm_persist<1><<<256, 512, 155648, stream>>>(p);
  }
  reduce_w_kernel<<<128, 64, 0, stream>>>(p.wpart, (const float*)d_in[18], p.w);
  final_kernel<<<1, 320, 0, stream>>>(p.w, (const float*)d_in[19],
                                      (const float*)d_in[20], (float*)d_out);
}

// Round 13
// 1315.183 us; speedup vs baseline: 1.1007x; 1.0034x over previous
//
#include <hip/hip_runtime.h>
#include <cstddef>
#include <cstdint>

typedef _Float16 half8 __attribute__((ext_vector_type(8)));
typedef float f32x4 __attribute__((ext_vector_type(4)));

#define S_LEN 128
#define B_SZ  64
#define E_SZ  1024
#define NLBL  5
#define NPHASE 129
#define RP 772            // pre row-pitch (f32): /4 odd -> conflict-free b128

// ---------------- ws layouts (bytes) ----------------
#define WOFF_WREC  0ull
#define WOFF_WINP  25165824ull
#define WOFF_X16   50331648ull
// MODE0 (history): h0 [2][129][64][1024] f16, h1 same
#define M0_H0    67108864ull
#define M0_H1    100925440ull
#define M0_WPART 134742016ull
#define M0_W     138936320ull
#define M0_FLAGS 138969088ull
#define NEED0    139001856ull
// MODE1 (2-buffer): h0 [2][2][64][1024] f16, h1 same
#define M1_H0    67108864ull
#define M1_H1    67633152ull
#define M1_WPART 68157440ull
#define M1_W     72351744ull
#define M1_FLAGS 72384512ull
#define NEED1    72417280ull

struct PP {
  const float* x;
  const float* W[2][3];
  const float* bias[2][3];
  const float* wordW;
  const float* cs0;
  _Float16* wrec;   // [(d*2+l)*64+j16][g*16384 + kc*512 + lane*8 + e] f16
  _Float16* winp;
  _Float16* x16;    // [B][S][E] f16
  _Float16* h0;     // MODE0: [2][129][64][1024]; MODE1: [2][2][64][1024]
  _Float16* h1;
  float* w;         // [64][128]
  float* wpart;     // [2d][64 j16][128 t][64 b]
  int* flags;       // [2d][128] stride-32 ints (128B)
};

__device__ __forceinline__ uint32_t pack2f16(float a, float b) {
  return (uint32_t)__builtin_bit_cast(unsigned short, (_Float16)a) |
         ((uint32_t)__builtin_bit_cast(unsigned short, (_Float16)b) << 16);
}

__device__ __forceinline__ float fast_sigmoid(float x) {
  return 1.f / (1.f + __expf(-x));
}
__device__ __forceinline__ float fast_tanh(float x) {
  return 1.f - 2.f / (__expf(2.f * x) + 1.f);   // saturates to +/-1, NaN-free
}

#define MFMA16(A, B, C) __builtin_amdgcn_mfma_f32_16x16x32_f16(A, B, C, 0, 0, 0)

// ---- issue asm primitives (outputs only -> no tied operands) ----
#define S_ISSUE_A4C(Q, P0, P1, P2, P3)                                     \
  asm volatile("global_load_dwordx4 %0, %4, off sc0 sc1\n\t"               \
               "global_load_dwordx4 %1, %5, off sc0 sc1\n\t"               \
               "global_load_dwordx4 %2, %6, off sc0 sc1\n\t"               \
               "global_load_dwordx4 %3, %7, off sc0 sc1"                   \
               : "=&v"((Q)[0]), "=&v"((Q)[1]), "=&v"((Q)[2]), "=&v"((Q)[3]) \
               : "v"(P0), "v"(P1), "v"(P2), "v"(P3))

#define S_ISSUE_A4P(Q, P0, P1, P2, P3)                                     \
  asm volatile("global_load_dwordx4 %0, %4, off\n\t"                       \
               "global_load_dwordx4 %1, %5, off\n\t"                       \
               "global_load_dwordx4 %2, %6, off\n\t"                       \
               "global_load_dwordx4 %3, %7, off"                           \
               : "=&v"((Q)[0]), "=&v"((Q)[1]), "=&v"((Q)[2]), "=&v"((Q)[3]) \
               : "v"(P0), "v"(P1), "v"(P2), "v"(P3))

// counted wait: bare asm + sched_barrier fence (rule-18 pattern)
#define S_WAITV(N)                                                         \
  asm volatile("s_waitcnt vmcnt(" #N ")" ::: "memory");                    \
  __builtin_amdgcn_sched_barrier(0)

// q[0],q[1] = m-tiles @ kcA; q[2],q[3] = m-tiles @ kcA+1; B from LDS
__device__ __forceinline__ void comp_rec2s(const uint4* q, int kcA,
                                           const _Float16* wlds, int l64,
                                           f32x4 acc[3][2]) {
  #pragma unroll
  for (int s = 0; s < 2; ++s) {
    const int kc = kcA + s;
    const half8 a0 = __builtin_bit_cast(half8, q[s * 2 + 0]);
    const half8 a1 = __builtin_bit_cast(half8, q[s * 2 + 1]);
    #pragma unroll
    for (int g = 0; g < 3; ++g) {
      const half8 bf = *(const half8*)(wlds + ((size_t)(g * 32 + kc) * 64 + l64) * 8);
      acc[g][0] = MFMA16(a0, bf, acc[g][0]);
      acc[g][1] = MFMA16(a1, bf, acc[g][1]);
    }
  }
}

// B from registers (winp slice)
__device__ __forceinline__ void comp_inp2(const uint4* aq, const uint4* wq,
                                          f32x4 acc[3][2]) {
  #pragma unroll
  for (int s = 0; s < 2; ++s) {
    const half8 a0 = __builtin_bit_cast(half8, aq[s * 2 + 0]);
    const half8 a1 = __builtin_bit_cast(half8, aq[s * 2 + 1]);
    #pragma unroll
    for (int g = 0; g < 3; ++g) {
      const half8 bf = __builtin_bit_cast(half8, wq[s * 3 + g]);
      acc[g][0] = MFMA16(a0, bf, acc[g][0]);
      acc[g][1] = MFMA16(a1, bf, acc[g][1]);
    }
  }
}

// -------- conversion kernels (run every launch; deterministic) --------
__global__ __launch_bounds__(256)
void conv_w_kernel(PP p) {
  const int blk = blockIdx.x;           // (((d*2+l)*3+g)*64 + j16)*2 + part
  const int part = blk & 1;
  const int j16 = (blk >> 1) & 63;
  const int rest = blk >> 7;
  const int g = rest % 3;
  const int dl = rest / 3;
  const int l = dl & 1, d = dl >> 1;
  const int tid = threadIdx.x;
  const int l2 = tid & 63, kc0 = tid >> 6;
  const float* W = p.W[d][g] + (size_t)l * 2048 * 1024 + (size_t)(part ? 1024 : 0) * 1024;
  _Float16* out = (part ? p.winp : p.wrec) + (size_t)(dl * 64 + j16) * 49152 + (size_t)g * 16384;
  const int j = j16 * 16 + (l2 & 15);
  const int kbase = (l2 >> 4) * 8;
  #pragma unroll
  for (int ki = 0; ki < 8; ++ki) {
    const int kc = kc0 * 8 + ki;
    const int k0 = kc * 32 + kbase;
    half8 h;
    #pragma unroll
    for (int e2 = 0; e2 < 8; ++e2) h[e2] = (_Float16)W[(size_t)(k0 + e2) * 1024 + j];
    *(half8*)(out + ((size_t)kc * 64 + l2) * 8) = h;
  }
}

__global__ __launch_bounds__(256)
void conv_x_kernel(const float* x, _Float16* x16) {
  const size_t i8 = ((size_t)blockIdx.x * 256 + threadIdx.x) * 8;
  float4 a = *(const float4*)(x + i8);
  float4 b = *(const float4*)(x + i8 + 4);
  half8 h;
  h[0] = (_Float16)a.x; h[1] = (_Float16)a.y; h[2] = (_Float16)a.z; h[3] = (_Float16)a.w;
  h[4] = (_Float16)b.x; h[5] = (_Float16)b.y; h[6] = (_Float16)b.z; h[7] = (_Float16)b.w;
  *(half8*)(x16 + i8) = h;
}

// MODE0: fill slot 0 of h0/h1 hist; MODE1: fill both par buffers. Then flags.
template<int MODE>
__global__ __launch_bounds__(256)
void init2_kernel(PP p, const float* hs) {
  const size_t HU = (MODE == 0) ? 65536 : 131072;  // u32 words per h array
  const size_t i = (size_t)blockIdx.x * 256 + threadIdx.x;
  if (i < 2 * HU) {
    const size_t ai = (i < HU) ? i : i - HU;
    _Float16* dst = (i < HU) ? p.h0 : p.h1;
    const size_t grp = ai >> 15;            // MODE0: d (0..1); MODE1: d*2+par (0..3)
    const size_t be = ai & 32767;           // [64][512] u32
    const size_t b = be >> 9, ec = be & 511;
    const uint32_t v = pack2f16(hs[b * 1024 + ec * 2], hs[b * 1024 + ec * 2 + 1]);
    const size_t u32off = (MODE == 0) ? (grp * 129 * 32768 + be) : (grp * 32768 + be);
    ((uint32_t*)dst)[u32off] = v;
  } else if (i < 2 * HU + 8192) {
    p.flags[i - 2 * HU] = 0;
  }
}

// ---------------- persistent bidirectional LSTM ----------------
template<int MODE>
__global__ __launch_bounds__(512, 2)
void lstm_persist(PP p) {
  extern __shared__ char smem[];
  _Float16* wlds = (_Float16*)smem;            // 98304 B: rec weights
  float* pre  = (float*)(smem + 98304);        // [16 cols][RP=772 rows] f32 = 49408 B
  float* wred = (float*)(smem + 147712);       // 4096 B

  const int tid = threadIdx.x;
  const int l64 = tid & 63, lr = l64 & 15, lg = l64 >> 4;
  const int wv = tid >> 6, kq = wv & 3, mg = wv >> 2;
  const int blk = blockIdx.x;
  const int j16 = blk & 63, l = (blk >> 6) & 1, d = blk >> 7;
  const int idx = blk & 127;
  const int j0 = j16 * 16;

  // kill stale L1/L2 lines from previous graph replays (one buffer_inv/block)
  if (tid == 0)
    (void)__hip_atomic_load(p.flags, __ATOMIC_ACQUIRE, __HIP_MEMORY_SCOPE_AGENT);
  __syncthreads();

  const size_t tileoff = (size_t)((d * 2 + l) * 64 + j16) * 49152;
  {
    const float4* src = (const float4*)(p.wrec + tileoff);
    float4* dst = (float4*)wlds;
    #pragma unroll
    for (int i = 0; i < 12; ++i) dst[tid + i * 512] = src[tid + i * 512];
  }
  const _Float16* wtile = p.winp + tileoff;
  _Float16* hrec_arr = l ? p.h1 : p.h0;

  // ---- winp slice -> registers (96 VGPR), reused all 129 phases ----
  uint4 wreg[24];
  #pragma unroll
  for (int i = 0; i < 24; ++i) {
    const int kcl = i / 3, g = i % 3;
    const int kc = kq * 8 + kcl;
    wreg[i] = *(const uint4*)(wtile + ((size_t)(g * 32 + kc) * 64 + l64) * 8);
  }

  // ---- prologue hoists: bias / wordW / c-state live in registers ----
  const int pr = tid >> 3;          // pointwise row 0..63
  const int pj = (tid & 7) * 2;     // pointwise col pair
  const int pjg = j0 + pj;
  const float bsf0 = p.bias[d][0][l * E_SZ + pjg], bsf1 = p.bias[d][0][l * E_SZ + pjg + 1];
  const float bsi0 = p.bias[d][1][l * E_SZ + pjg], bsi1 = p.bias[d][1][l * E_SZ + pjg + 1];
  const float bsc0 = p.bias[d][2][l * E_SZ + pjg], bsc1 = p.bias[d][2][l * E_SZ + pjg + 1];
  const float ww0 = p.wordW[d * E_SZ + pjg], ww1 = p.wordW[d * E_SZ + pjg + 1];
  float creg0 = p.cs0[(size_t)pr * E_SZ + pjg];
  float creg1 = p.cs0[(size_t)pr * E_SZ + pjg + 1];
  __syncthreads();

  auto hoff = [&](int dd, int s) -> size_t {
    return (MODE == 0) ? ((size_t)dd * 129 + s) * 65536 : ((size_t)(dd * 2 + s)) * 65536;
  };

  for (int ph = 0; ph < NPHASE; ++ph) {
    const int t = l ? (ph - 1) : ph;
    const bool active = (unsigned)t < (unsigned)S_LEN;
    if (active) {
      const int par = t & 1, prev = par ^ 1;
      const int td = d ? (S_LEN - 1 - t) : t;
      const int rs    = (MODE == 0) ? t : prev;       // recurrent read slot
      const int wslot = (MODE == 0) ? (t + 1) : par;  // write slot
      const int islot = (MODE == 0) ? (t + 1) : par;  // l1 input slot (h0)

      const _Float16* hAf = hrec_arr + hoff(d, rs);
      const _Float16* r0 = hAf + (size_t)(mg * 32 + lr) * 1024;
      const _Float16* r1 = hAf + (size_t)(mg * 32 + 16 + lr) * 1024;
      const _Float16* a0base;
      const _Float16* a1base;
      if (l == 0) {
        a0base = p.x16 + ((size_t)(mg * 32 + lr) * S_LEN + td) * 1024;
        a1base = p.x16 + ((size_t)(mg * 32 + 16 + lr) * S_LEN + td) * 1024;
      } else {
        const _Float16* hf = p.h0 + hoff(d, islot);
        a0base = hf + (size_t)(mg * 32 + lr) * 1024;
        a1base = hf + (size_t)(mg * 32 + 16 + lr) * 1024;
      }

      const f32x4 zero = {0.f, 0.f, 0.f, 0.f};
      f32x4 acc[3][2];
      #pragma unroll
      for (int g = 0; g < 3; ++g) { acc[g][0] = zero; acc[g][1] = zero; }

      auto issue_rec = [&](int c, uint4* Q) {
        const int kk = (kq * 8 + c * 2) * 32 + lg * 8;
        if (MODE == 0) {
          S_ISSUE_A4P(Q, r0 + kk, r1 + kk, r0 + kk + 32, r1 + kk + 32);
        } else {
          S_ISSUE_A4C(Q, r0 + kk, r1 + kk, r0 + kk + 32, r1 + kk + 32);
        }
      };
      auto issue_a = [&](int c, uint4* Q) {
        const int kk = (kq * 8 + c * 2) * 32 + lg * 8;
        if (MODE == 0 || l == 0) {
          S_ISSUE_A4P(Q, a0base + kk, a1base + kk, a0base + kk + 32, a1base + kk + 32);
        } else {
          S_ISSUE_A4C(Q, a0base + kk, a1base + kk, a0base + kk + 32, a1base + kk + 32);
        }
      };

      // ---- 3-buffer, 8-stage pipeline (s0-3 rec, s4-7 input), vmcnt(8) ----
      uint4 b0[4], b1[4], b2[4];
      issue_rec(0, b0); issue_rec(1, b1); issue_rec(2, b2);
      S_WAITV(8); comp_rec2s(b0, kq * 8 + 0, wlds, l64, acc); issue_rec(3, b0);
      S_WAITV(8); comp_rec2s(b1, kq * 8 + 2, wlds, l64, acc); issue_a(0, b1);
      S_WAITV(8); comp_rec2s(b2, kq * 8 + 4, wlds, l64, acc); issue_a(1, b2);
      S_WAITV(8); comp_rec2s(b0, kq * 8 + 6, wlds, l64, acc); issue_a(2, b0);
      S_WAITV(8); comp_inp2(b1, &wreg[0],  acc); issue_a(3, b1);
      S_WAITV(8); comp_inp2(b2, &wreg[6],  acc);
      S_WAITV(4); comp_inp2(b0, &wreg[12], acc);
      S_WAITV(0); comp_inp2(b1, &wreg[18], acc);

      // ---- reduce kq partials: transposed pre[col][row], b128 writes ----
      // RP/4 = 193 (odd) -> lane bank-quads uniform -> conflict-free
      #pragma unroll
      for (int g = 0; g < 3; ++g)
        #pragma unroll
        for (int mt = 0; mt < 2; ++mt) {
          const int row0 = ((kq * 3 + g) * 64) + (mg * 2 + mt) * 16 + lg * 4;
          *(f32x4*)&pre[lr * RP + row0] = acc[g][mt];
        }
      __syncthreads();

      // ---- pointwise LSTM update (1 row x 2 cols per thread) ----
      float fp0 = bsf0, fp1 = bsf1, ip0 = bsi0, ip1 = bsi1, cp0 = bsc0, cp1 = bsc1;
      #pragma unroll
      for (int k = 0; k < 4; ++k) {
        fp0 += pre[pj * RP + (k * 3 + 0) * 64 + pr];
        fp1 += pre[(pj + 1) * RP + (k * 3 + 0) * 64 + pr];
        ip0 += pre[pj * RP + (k * 3 + 1) * 64 + pr];
        ip1 += pre[(pj + 1) * RP + (k * 3 + 1) * 64 + pr];
        cp0 += pre[pj * RP + (k * 3 + 2) * 64 + pr];
        cp1 += pre[(pj + 1) * RP + (k * 3 + 2) * 64 + pr];
      }
      const float fg0 = fast_sigmoid(fp0), fg1 = fast_sigmoid(fp1);
      const float ig0 = fast_sigmoid(ip0), ig1 = fast_sigmoid(ip1);
      const float gg0 = fast_tanh(cp0), gg1 = fast_tanh(cp1);
      creg0 = creg0 * fg0 + ig0 * gg0;
      creg1 = creg1 * fg1 + ig1 * gg1;
      const float h0v = fast_tanh(creg0) * fg0;   // forget gate reused as output gate
      const float h1v = fast_tanh(creg1) * fg1;

      uint32_t* hdst = (uint32_t*)(hrec_arr + hoff(d, wslot) + (size_t)pr * 1024 + pjg);
      const uint32_t pk = pack2f16(h0v, h1v);
      asm volatile("global_store_dword %0, %1, off sc0 sc1" ::"v"(hdst), "v"(pk) : "memory");
      if (l) {
        wred[pr * 16 + pj] = h0v * ww0;
        wred[pr * 16 + pj + 1] = h1v * ww1;
      }
      // ---- announce completion right after the h-store drain ----
      __syncthreads();   // compiler drains vmcnt before s_barrier -> h visible
      if (tid == 0) {
        __hip_atomic_store(p.flags + (size_t)(d * 128 + idx) * 32, ph + 1,
                           __ATOMIC_RELAXED, __HIP_MEMORY_SCOPE_AGENT);
        asm volatile("s_waitcnt vmcnt(0)" ::: "memory");
      }
      // ---- word-projection partials (off inter-block critical path) ----
      if (l && tid < 64) {
        float s = 0.f;
        #pragma unroll
        for (int q = 0; q < 16; ++q) s += wred[tid * 16 + q];
        p.wpart[((size_t)(d * 64 + j16) * S_LEN + td) * 64 + tid] = s;
      }
    } else {
      __syncthreads();
      if (tid == 0) {
        __hip_atomic_store(p.flags + (size_t)(d * 128 + idx) * 32, ph + 1,
                           __ATOMIC_RELAXED, __HIP_MEMORY_SCOPE_AGENT);
        asm volatile("s_waitcnt vmcnt(0)" ::: "memory");
      }
    }

    // ---- flat 1-hop barrier: parallel poll of all 128 group flags ----
    if (tid < 128) {
      const int* fl = p.flags + (size_t)(d * 128 + tid) * 32;
      int f, it = 0;
      do {
        f = __hip_atomic_load(fl, __ATOMIC_RELAXED, __HIP_MEMORY_SCOPE_AGENT);
        if (f >= ph + 1) break;
        __builtin_amdgcn_s_sleep(1);
      } while (++it < (1 << 22));
    }
    __syncthreads();
  }
}

// w[b][t] = word_b + sum over (d,j16) of wpart
__global__ __launch_bounds__(64)
void reduce_w_kernel(const float* wpart, const float* wordb, float* w) {
  const int t = blockIdx.x, b = threadIdx.x;
  float s = wordb[0];
  #pragma unroll 8
  for (int q = 0; q < 128; ++q)
    s += wpart[((size_t)q * S_LEN + t) * 64 + b];
  w[b * S_LEN + t] = s;
}

__global__ __launch_bounds__(320)
void final_kernel(const float* w, const float* predW, const float* predb, float* out) {
  const int tid = threadIdx.x;
  if (tid >= B_SZ * NLBL) return;
  const int b = tid / NLBL, lab = tid % NLBL;
  float s = predb[lab];
  #pragma unroll 8
  for (int t = 0; t < S_LEN; ++t) s += w[b * S_LEN + t] * predW[t * NLBL + lab];
  out[tid] = s;
}

// ================= launcher =================
extern "C" void kernel_launch(void* const* d_in, const int* in_sizes, int n_in,
                              void* d_out, int out_size, void* d_ws, size_t ws_size,
                              hipStream_t stream) {
  char* ws = (char*)d_ws;
  const bool hist = (ws_size >= NEED0);

  PP p;
  p.x = (const float*)d_in[0];
  p.W[0][0] = (const float*)d_in[5];  p.bias[0][0] = (const float*)d_in[6];
  p.W[0][1] = (const float*)d_in[7];  p.bias[0][1] = (const float*)d_in[8];
  p.W[0][2] = (const float*)d_in[9];  p.bias[0][2] = (const float*)d_in[10];
  p.W[1][0] = (const float*)d_in[11]; p.bias[1][0] = (const float*)d_in[12];
  p.W[1][1] = (const float*)d_in[13]; p.bias[1][1] = (const float*)d_in[14];
  p.W[1][2] = (const float*)d_in[15]; p.bias[1][2] = (const float*)d_in[16];
  p.wordW = (const float*)d_in[17];
  p.cs0   = (const float*)d_in[1];
  p.wrec  = (_Float16*)(ws + WOFF_WREC);
  p.winp  = (_Float16*)(ws + WOFF_WINP);
  p.x16   = (_Float16*)(ws + WOFF_X16);
  if (hist) {
    p.h0    = (_Float16*)(ws + M0_H0);
    p.h1    = (_Float16*)(ws + M0_H1);
    p.wpart = (float*)(ws + M0_WPART);
    p.w     = (float*)(ws + M0_W);
    p.flags = (int*)(ws + M0_FLAGS);
  } else {
    p.h0    = (_Float16*)(ws + M1_H0);
    p.h1    = (_Float16*)(ws + M1_H1);
    p.wpart = (float*)(ws + M1_WPART);
    p.w     = (float*)(ws + M1_W);
    p.flags = (int*)(ws + M1_FLAGS);
  }

  hipFuncSetAttribute(reinterpret_cast<const void*>(&lstm_persist<0>),
                      hipFuncAttributeMaxDynamicSharedMemorySize, 151808);
  hipFuncSetAttribute(reinterpret_cast<const void*>(&lstm_persist<1>),
                      hipFuncAttributeMaxDynamicSharedMemorySize, 151808);

  conv_w_kernel<<<1536, 256, 0, stream>>>(p);
  conv_x_kernel<<<4096, 256, 0, stream>>>(p.x, p.x16);
  if (hist) {
    init2_kernel<0><<<544, 256, 0, stream>>>(p, (const float*)d_in[2]);
    lstm_persist<0><<<256, 512, 151808, stream>>>(p);
  } else {
    init2_kernel<1><<<1056, 256, 0, stream>>>(p, (const float*)d_in[2]);
    lstm_persist<1><<<256, 512, 151808, stream>>>(p);
  }
  reduce_w_kernel<<<128, 64, 0, stream>>>(p.wpart, (const float*)d_in[18], p.w);
  final_kernel<<<1, 320, 0, stream>>>(p.w, (const float*)d_in[19],
                                      (const float*)d_in[20], (float*)d_out);
}

// Round 14
// 1311.962 us; speedup vs baseline: 1.1034x; 1.0025x over previous
//
#include <hip/hip_runtime.h>
#include <cstddef>
#include <cstdint>

typedef _Float16 half8 __attribute__((ext_vector_type(8)));
typedef float f32x4 __attribute__((ext_vector_type(4)));

#define S_LEN 128
#define B_SZ  64
#define E_SZ  1024
#define NLBL  5
#define NPHASE 129
#define RP 772            // pre row-pitch (f32): /4 odd -> conflict-free b128

// ---------------- ws layouts (bytes) ----------------
#define WOFF_WREC  0ull
#define WOFF_WINP  25165824ull
#define WOFF_X16   50331648ull
// MODE0 (history): h0 [2][129][64][1024] f16, h1 same
#define M0_H0    67108864ull
#define M0_H1    100925440ull
#define M0_WPART 134742016ull
#define M0_W     138936320ull
#define M0_FLAGS 138969088ull
#define NEED0    139001856ull
// MODE1 (2-buffer): h0 [2][2][64][1024] f16, h1 same
#define M1_H0    67108864ull
#define M1_H1    67633152ull
#define M1_WPART 68157440ull
#define M1_W     72351744ull
#define M1_FLAGS 72384512ull
#define NEED1    72417280ull

struct PP {
  const float* x;
  const float* W[2][3];
  const float* bias[2][3];
  const float* wordW;
  const float* cs0;
  _Float16* wrec;   // [(d*2+l)*64+j16][g*16384 + kc*512 + lane*8 + e] f16
  _Float16* winp;
  _Float16* x16;    // [B][S][E] f16
  _Float16* h0;     // MODE0: [2][129][64][1024]; MODE1: [2][2][64][1024]
  _Float16* h1;
  float* w;         // [64][128]
  float* wpart;     // [2d][64 j16][128 t][64 b]
  int* flags;       // [2d][128] stride-32 ints (128B)
};

__device__ __forceinline__ uint32_t pack2f16(float a, float b) {
  return (uint32_t)__builtin_bit_cast(unsigned short, (_Float16)a) |
         ((uint32_t)__builtin_bit_cast(unsigned short, (_Float16)b) << 16);
}

__device__ __forceinline__ float fast_sigmoid(float x) {
  return 1.f / (1.f + __expf(-x));
}
__device__ __forceinline__ float fast_tanh(float x) {
  return 1.f - 2.f / (__expf(2.f * x) + 1.f);   // saturates to +/-1, NaN-free
}

#define MFMA16(A, B, C) __builtin_amdgcn_mfma_f32_16x16x32_f16(A, B, C, 0, 0, 0)

// ---- issue asm primitives (outputs only -> no tied operands) ----
#define S_ISSUE_A4C(Q, P0, P1, P2, P3)                                     \
  asm volatile("global_load_dwordx4 %0, %4, off sc0 sc1\n\t"               \
               "global_load_dwordx4 %1, %5, off sc0 sc1\n\t"               \
               "global_load_dwordx4 %2, %6, off sc0 sc1\n\t"               \
               "global_load_dwordx4 %3, %7, off sc0 sc1"                   \
               : "=&v"((Q)[0]), "=&v"((Q)[1]), "=&v"((Q)[2]), "=&v"((Q)[3]) \
               : "v"(P0), "v"(P1), "v"(P2), "v"(P3))

#define S_ISSUE_A4P(Q, P0, P1, P2, P3)                                     \
  asm volatile("global_load_dwordx4 %0, %4, off\n\t"                       \
               "global_load_dwordx4 %1, %5, off\n\t"                       \
               "global_load_dwordx4 %2, %6, off\n\t"                       \
               "global_load_dwordx4 %3, %7, off"                           \
               : "=&v"((Q)[0]), "=&v"((Q)[1]), "=&v"((Q)[2]), "=&v"((Q)[3]) \
               : "v"(P0), "v"(P1), "v"(P2), "v"(P3))

// counted wait: bare asm + sched_barrier fence (rule-18 pattern)
#define S_WAITV(N)                                                         \
  asm volatile("s_waitcnt vmcnt(" #N ")" ::: "memory");                    \
  __builtin_amdgcn_sched_barrier(0)

// q[0],q[1] = m-tiles @ kcA; q[2],q[3] = m-tiles @ kcA+1; B from LDS
__device__ __forceinline__ void comp_rec2s(const uint4* q, int kcA,
                                           const _Float16* wlds, int l64,
                                           f32x4 acc[3][2]) {
  #pragma unroll
  for (int s = 0; s < 2; ++s) {
    const int kc = kcA + s;
    const half8 a0 = __builtin_bit_cast(half8, q[s * 2 + 0]);
    const half8 a1 = __builtin_bit_cast(half8, q[s * 2 + 1]);
    #pragma unroll
    for (int g = 0; g < 3; ++g) {
      const half8 bf = *(const half8*)(wlds + ((size_t)(g * 32 + kc) * 64 + l64) * 8);
      acc[g][0] = MFMA16(a0, bf, acc[g][0]);
      acc[g][1] = MFMA16(a1, bf, acc[g][1]);
    }
  }
}

// B from registers (winp slice)
__device__ __forceinline__ void comp_inp2(const uint4* aq, const uint4* wq,
                                          f32x4 acc[3][2]) {
  #pragma unroll
  for (int s = 0; s < 2; ++s) {
    const half8 a0 = __builtin_bit_cast(half8, aq[s * 2 + 0]);
    const half8 a1 = __builtin_bit_cast(half8, aq[s * 2 + 1]);
    #pragma unroll
    for (int g = 0; g < 3; ++g) {
      const half8 bf = __builtin_bit_cast(half8, wq[s * 3 + g]);
      acc[g][0] = MFMA16(a0, bf, acc[g][0]);
      acc[g][1] = MFMA16(a1, bf, acc[g][1]);
    }
  }
}

// -------- conversion kernels (run every launch; deterministic) --------
__global__ __launch_bounds__(256)
void conv_w_kernel(PP p) {
  const int blk = blockIdx.x;           // (((d*2+l)*3+g)*64 + j16)*2 + part
  const int part = blk & 1;
  const int j16 = (blk >> 1) & 63;
  const int rest = blk >> 7;
  const int g = rest % 3;
  const int dl = rest / 3;
  const int l = dl & 1, d = dl >> 1;
  const int tid = threadIdx.x;
  const int l2 = tid & 63, kc0 = tid >> 6;
  const float* W = p.W[d][g] + (size_t)l * 2048 * 1024 + (size_t)(part ? 1024 : 0) * 1024;
  _Float16* out = (part ? p.winp : p.wrec) + (size_t)(dl * 64 + j16) * 49152 + (size_t)g * 16384;
  const int j = j16 * 16 + (l2 & 15);
  const int kbase = (l2 >> 4) * 8;
  #pragma unroll
  for (int ki = 0; ki < 8; ++ki) {
    const int kc = kc0 * 8 + ki;
    const int k0 = kc * 32 + kbase;
    half8 h;
    #pragma unroll
    for (int e2 = 0; e2 < 8; ++e2) h[e2] = (_Float16)W[(size_t)(k0 + e2) * 1024 + j];
    *(half8*)(out + ((size_t)kc * 64 + l2) * 8) = h;
  }
}

__global__ __launch_bounds__(256)
void conv_x_kernel(const float* x, _Float16* x16) {
  const size_t i8 = ((size_t)blockIdx.x * 256 + threadIdx.x) * 8;
  float4 a = *(const float4*)(x + i8);
  float4 b = *(const float4*)(x + i8 + 4);
  half8 h;
  h[0] = (_Float16)a.x; h[1] = (_Float16)a.y; h[2] = (_Float16)a.z; h[3] = (_Float16)a.w;
  h[4] = (_Float16)b.x; h[5] = (_Float16)b.y; h[6] = (_Float16)b.z; h[7] = (_Float16)b.w;
  *(half8*)(x16 + i8) = h;
}

// MODE0: fill slot 0 of h0/h1 hist; MODE1: fill both par buffers. Then flags.
template<int MODE>
__global__ __launch_bounds__(256)
void init2_kernel(PP p, const float* hs) {
  const size_t HU = (MODE == 0) ? 65536 : 131072;  // u32 words per h array
  const size_t i = (size_t)blockIdx.x * 256 + threadIdx.x;
  if (i < 2 * HU) {
    const size_t ai = (i < HU) ? i : i - HU;
    _Float16* dst = (i < HU) ? p.h0 : p.h1;
    const size_t grp = ai >> 15;            // MODE0: d (0..1); MODE1: d*2+par (0..3)
    const size_t be = ai & 32767;           // [64][512] u32
    const size_t b = be >> 9, ec = be & 511;
    const uint32_t v = pack2f16(hs[b * 1024 + ec * 2], hs[b * 1024 + ec * 2 + 1]);
    const size_t u32off = (MODE == 0) ? (grp * 129 * 32768 + be) : (grp * 32768 + be);
    ((uint32_t*)dst)[u32off] = v;
  } else if (i < 2 * HU + 8192) {
    p.flags[i - 2 * HU] = 0;
  }
}

// ---------------- persistent bidirectional LSTM ----------------
template<int MODE>
__global__ __launch_bounds__(512, 2)
void lstm_persist(PP p) {
  extern __shared__ char smem[];
  _Float16* wlds = (_Float16*)smem;            // 98304 B: rec weights
  float* pre  = (float*)(smem + 98304);        // [16 cols][RP=772 rows] f32 = 49408 B
  float* wred = (float*)(smem + 147712);       // 4096 B

  const int tid = threadIdx.x;
  const int l64 = tid & 63, lr = l64 & 15, lg = l64 >> 4;
  const int wv = tid >> 6, kq = wv & 3, mg = wv >> 2;
  const int blk = blockIdx.x;
  const int j16 = blk & 63, l = (blk >> 6) & 1, d = blk >> 7;
  const int idx = blk & 127;
  const int j0 = j16 * 16;

  // kill stale L1/L2 lines from previous graph replays (one buffer_inv/block)
  if (tid == 0)
    (void)__hip_atomic_load(p.flags, __ATOMIC_ACQUIRE, __HIP_MEMORY_SCOPE_AGENT);
  __syncthreads();

  const size_t tileoff = (size_t)((d * 2 + l) * 64 + j16) * 49152;
  {
    const float4* src = (const float4*)(p.wrec + tileoff);
    float4* dst = (float4*)wlds;
    #pragma unroll
    for (int i = 0; i < 12; ++i) dst[tid + i * 512] = src[tid + i * 512];
  }
  const _Float16* wtile = p.winp + tileoff;
  _Float16* hrec_arr = l ? p.h1 : p.h0;

  // ---- winp slice -> registers (96 VGPR), reused all 129 phases ----
  uint4 wreg[24];
  #pragma unroll
  for (int i = 0; i < 24; ++i) {
    const int kcl = i / 3, g = i % 3;
    const int kc = kq * 8 + kcl;
    wreg[i] = *(const uint4*)(wtile + ((size_t)(g * 32 + kc) * 64 + l64) * 8);
  }

  // ---- prologue hoists: bias / wordW / c-state live in registers ----
  const int pr = tid >> 3;          // pointwise row 0..63
  const int pj = (tid & 7) * 2;     // pointwise col pair
  const int pjg = j0 + pj;
  const float bsf0 = p.bias[d][0][l * E_SZ + pjg], bsf1 = p.bias[d][0][l * E_SZ + pjg + 1];
  const float bsi0 = p.bias[d][1][l * E_SZ + pjg], bsi1 = p.bias[d][1][l * E_SZ + pjg + 1];
  const float bsc0 = p.bias[d][2][l * E_SZ + pjg], bsc1 = p.bias[d][2][l * E_SZ + pjg + 1];
  const float ww0 = p.wordW[d * E_SZ + pjg], ww1 = p.wordW[d * E_SZ + pjg + 1];
  float creg0 = p.cs0[(size_t)pr * E_SZ + pjg];
  float creg1 = p.cs0[(size_t)pr * E_SZ + pjg + 1];
  __syncthreads();

  auto hoff = [&](int dd, int s) -> size_t {
    return (MODE == 0) ? ((size_t)dd * 129 + s) * 65536 : ((size_t)(dd * 2 + s)) * 65536;
  };

  for (int ph = 0; ph < NPHASE; ++ph) {
    const int t = l ? (ph - 1) : ph;
    const bool active = (unsigned)t < (unsigned)S_LEN;
    if (active) {
      const int par = t & 1, prev = par ^ 1;
      const int td = d ? (S_LEN - 1 - t) : t;
      const int rs    = (MODE == 0) ? t : prev;       // recurrent read slot
      const int wslot = (MODE == 0) ? (t + 1) : par;  // write slot
      const int islot = (MODE == 0) ? (t + 1) : par;  // l1 input slot (h0)

      const _Float16* hAf = hrec_arr + hoff(d, rs);
      const _Float16* r0 = hAf + (size_t)(mg * 32 + lr) * 1024;
      const _Float16* r1 = hAf + (size_t)(mg * 32 + 16 + lr) * 1024;
      const _Float16* a0base;
      const _Float16* a1base;
      if (l == 0) {
        a0base = p.x16 + ((size_t)(mg * 32 + lr) * S_LEN + td) * 1024;
        a1base = p.x16 + ((size_t)(mg * 32 + 16 + lr) * S_LEN + td) * 1024;
      } else {
        const _Float16* hf = p.h0 + hoff(d, islot);
        a0base = hf + (size_t)(mg * 32 + lr) * 1024;
        a1base = hf + (size_t)(mg * 32 + 16 + lr) * 1024;
      }

      const f32x4 zero = {0.f, 0.f, 0.f, 0.f};
      f32x4 acc[3][2];
      #pragma unroll
      for (int g = 0; g < 3; ++g) { acc[g][0] = zero; acc[g][1] = zero; }

      auto issue_rec = [&](int c, uint4* Q) {
        const int kk = (kq * 8 + c * 2) * 32 + lg * 8;
        if (MODE == 0) {
          S_ISSUE_A4P(Q, r0 + kk, r1 + kk, r0 + kk + 32, r1 + kk + 32);
        } else {
          S_ISSUE_A4C(Q, r0 + kk, r1 + kk, r0 + kk + 32, r1 + kk + 32);
        }
      };
      auto issue_a = [&](int c, uint4* Q) {
        const int kk = (kq * 8 + c * 2) * 32 + lg * 8;
        if (MODE == 0 || l == 0) {
          S_ISSUE_A4P(Q, a0base + kk, a1base + kk, a0base + kk + 32, a1base + kk + 32);
        } else {
          S_ISSUE_A4C(Q, a0base + kk, a1base + kk, a0base + kk + 32, a1base + kk + 32);
        }
      };

      // ---- 3-buffer, 8-stage pipeline (s0-3 rec, s4-7 input), vmcnt(8) ----
      uint4 b0[4], b1[4], b2[4];
      issue_rec(0, b0); issue_rec(1, b1); issue_rec(2, b2);
      S_WAITV(8); comp_rec2s(b0, kq * 8 + 0, wlds, l64, acc); issue_rec(3, b0);
      S_WAITV(8); comp_rec2s(b1, kq * 8 + 2, wlds, l64, acc); issue_a(0, b1);
      S_WAITV(8); comp_rec2s(b2, kq * 8 + 4, wlds, l64, acc); issue_a(1, b2);
      S_WAITV(8); comp_rec2s(b0, kq * 8 + 6, wlds, l64, acc); issue_a(2, b0);
      S_WAITV(8); comp_inp2(b1, &wreg[0],  acc); issue_a(3, b1);
      S_WAITV(8); comp_inp2(b2, &wreg[6],  acc);
      S_WAITV(4); comp_inp2(b0, &wreg[12], acc);
      S_WAITV(0); comp_inp2(b1, &wreg[18], acc);

      // ---- reduce kq partials: transposed pre[col][row], b128 writes ----
      // RP/4 = 193 (odd) -> lane bank-quads uniform -> conflict-free
      #pragma unroll
      for (int g = 0; g < 3; ++g)
        #pragma unroll
        for (int mt = 0; mt < 2; ++mt) {
          const int row0 = ((kq * 3 + g) * 64) + (mg * 2 + mt) * 16 + lg * 4;
          *(f32x4*)&pre[lr * RP + row0] = acc[g][mt];
        }
      __syncthreads();

      // ---- pointwise LSTM update (1 row x 2 cols per thread) ----
      float fp0 = bsf0, fp1 = bsf1, ip0 = bsi0, ip1 = bsi1, cp0 = bsc0, cp1 = bsc1;
      #pragma unroll
      for (int k = 0; k < 4; ++k) {
        fp0 += pre[pj * RP + (k * 3 + 0) * 64 + pr];
        fp1 += pre[(pj + 1) * RP + (k * 3 + 0) * 64 + pr];
        ip0 += pre[pj * RP + (k * 3 + 1) * 64 + pr];
        ip1 += pre[(pj + 1) * RP + (k * 3 + 1) * 64 + pr];
        cp0 += pre[pj * RP + (k * 3 + 2) * 64 + pr];
        cp1 += pre[(pj + 1) * RP + (k * 3 + 2) * 64 + pr];
      }
      const float fg0 = fast_sigmoid(fp0), fg1 = fast_sigmoid(fp1);
      const float ig0 = fast_sigmoid(ip0), ig1 = fast_sigmoid(ip1);
      const float gg0 = fast_tanh(cp0), gg1 = fast_tanh(cp1);
      creg0 = creg0 * fg0 + ig0 * gg0;
      creg1 = creg1 * fg1 + ig1 * gg1;
      const float h0v = fast_tanh(creg0) * fg0;   // forget gate reused as output gate
      const float h1v = fast_tanh(creg1) * fg1;

      uint32_t* hdst = (uint32_t*)(hrec_arr + hoff(d, wslot) + (size_t)pr * 1024 + pjg);
      const uint32_t pk = pack2f16(h0v, h1v);
      asm volatile("global_store_dword %0, %1, off sc0 sc1" ::"v"(hdst), "v"(pk) : "memory");
      if (l) {
        wred[pr * 16 + pj] = h0v * ww0;
        wred[pr * 16 + pj + 1] = h1v * ww1;
      }
      // ---- announce completion right after the h-store drain ----
      __syncthreads();   // compiler drains vmcnt before s_barrier -> h visible
      if (tid == 0) {
        __hip_atomic_store(p.flags + (size_t)(d * 128 + idx) * 32, ph + 1,
                           __ATOMIC_RELAXED, __HIP_MEMORY_SCOPE_AGENT);
        asm volatile("s_waitcnt vmcnt(0)" ::: "memory");
      }
      // ---- word-projection partials (off inter-block critical path) ----
      if (l && tid < 64) {
        float s = 0.f;
        #pragma unroll
        for (int q = 0; q < 16; ++q) s += wred[tid * 16 + q];
        p.wpart[((size_t)(d * 64 + j16) * S_LEN + td) * 64 + tid] = s;
      }
    } else {
      __syncthreads();
      if (tid == 0) {
        __hip_atomic_store(p.flags + (size_t)(d * 128 + idx) * 32, ph + 1,
                           __ATOMIC_RELAXED, __HIP_MEMORY_SCOPE_AGENT);
        asm volatile("s_waitcnt vmcnt(0)" ::: "memory");
      }
    }

    // ---- bounded-skew barrier poll ----
    // MODE0: write-once h slots => l0 has NO data edge from l1. l0 waits own
    // group fully (>= ph+1) but allows l1 to lag by up to 2 phases (>= ph-1).
    // l1 (and all of MODE1) waits all 128 flags >= ph+1.
    if (tid < 128) {
      const int need = (MODE == 0 && l == 0 && tid >= 64) ? (ph - 1) : (ph + 1);
      const int* fl = p.flags + (size_t)(d * 128 + tid) * 32;
      int f, it = 0;
      do {
        f = __hip_atomic_load(fl, __ATOMIC_RELAXED, __HIP_MEMORY_SCOPE_AGENT);
        if (f >= need) break;
        __builtin_amdgcn_s_sleep(1);
      } while (++it < (1 << 22));
    }
    __syncthreads();
  }
}

// w[b][t] = word_b + sum over (d,j16) of wpart
__global__ __launch_bounds__(64)
void reduce_w_kernel(const float* wpart, const float* wordb, float* w) {
  const int t = blockIdx.x, b = threadIdx.x;
  float s = wordb[0];
  #pragma unroll 8
  for (int q = 0; q < 128; ++q)
    s += wpart[((size_t)q * S_LEN + t) * 64 + b];
  w[b * S_LEN + t] = s;
}

__global__ __launch_bounds__(320)
void final_kernel(const float* w, const float* predW, const float* predb, float* out) {
  const int tid = threadIdx.x;
  if (tid >= B_SZ * NLBL) return;
  const int b = tid / NLBL, lab = tid % NLBL;
  float s = predb[lab];
  #pragma unroll 8
  for (int t = 0; t < S_LEN; ++t) s += w[b * S_LEN + t] * predW[t * NLBL + lab];
  out[tid] = s;
}

// ================= launcher =================
extern "C" void kernel_launch(void* const* d_in, const int* in_sizes, int n_in,
                              void* d_out, int out_size, void* d_ws, size_t ws_size,
                              hipStream_t stream) {
  char* ws = (char*)d_ws;
  const bool hist = (ws_size >= NEED0);

  PP p;
  p.x = (const float*)d_in[0];
  p.W[0][0] = (const float*)d_in[5];  p.bias[0][0] = (const float*)d_in[6];
  p.W[0][1] = (const float*)d_in[7];  p.bias[0][1] = (const float*)d_in[8];
  p.W[0][2] = (const float*)d_in[9];  p.bias[0][2] = (const float*)d_in[10];
  p.W[1][0] = (const float*)d_in[11]; p.bias[1][0] = (const float*)d_in[12];
  p.W[1][1] = (const float*)d_in[13]; p.bias[1][1] = (const float*)d_in[14];
  p.W[1][2] = (const float*)d_in[15]; p.bias[1][2] = (const float*)d_in[16];
  p.wordW = (const float*)d_in[17];
  p.cs0   = (const float*)d_in[1];
  p.wrec  = (_Float16*)(ws + WOFF_WREC);
  p.winp  = (_Float16*)(ws + WOFF_WINP);
  p.x16   = (_Float16*)(ws + WOFF_X16);
  if (hist) {
    p.h0    = (_Float16*)(ws + M0_H0);
    p.h1    = (_Float16*)(ws + M0_H1);
    p.wpart = (float*)(ws + M0_WPART);
    p.w     = (float*)(ws + M0_W);
    p.flags = (int*)(ws + M0_FLAGS);
  } else {
    p.h0    = (_Float16*)(ws + M1_H0);
    p.h1    = (_Float16*)(ws + M1_H1);
    p.wpart = (float*)(ws + M1_WPART);
    p.w     = (float*)(ws + M1_W);
    p.flags = (int*)(ws + M1_FLAGS);
  }

  hipFuncSetAttribute(reinterpret_cast<const void*>(&lstm_persist<0>),
                      hipFuncAttributeMaxDynamicSharedMemorySize, 151808);
  hipFuncSetAttribute(reinterpret_cast<const void*>(&lstm_persist<1>),
                      hipFuncAttributeMaxDynamicSharedMemorySize, 151808);

  conv_w_kernel<<<1536, 256, 0, stream>>>(p);
  conv_x_kernel<<<4096, 256, 0, stream>>>(p.x, p.x16);
  if (hist) {
    init2_kernel<0><<<544, 256, 0, stream>>>(p, (const float*)d_in[2]);
    lstm_persist<0><<<256, 512, 151808, stream>>>(p);
  } else {
    init2_kernel<1><<<1056, 256, 0, stream>>>(p, (const float*)d_in[2]);
    lstm_persist<1><<<256, 512, 151808, stream>>>(p);
  }
  reduce_w_kernel<<<128, 64, 0, stream>>>(p.wpart, (const float*)d_in[18], p.w);
  final_kernel<<<1, 320, 0, stream>>>(p.w, (const float*)d_in[19],
                                      (const float*)d_in[20], (float*)d_out);
}